// Round 8
// baseline (120.099 us; speedup 1.0000x reference)
//
#include <hip/hip_runtime.h>
#include <hip/hip_bf16.h>

// DenseGridNet R8: two-pass, both phases restructured.
//  conv_emb: fp32 emb -> bf16 table (8 MB)
//  gather3 : 4 pts/thread, 16 texel loads in flight -> packed bf16 in8
//  mlp3    : no-Lin no-Lo MFMA pass: direct A-frag global loads (prefetch d2),
//            direct coalesced out stores, 2 fences/tile, (256,4) = 16 waves/CU.
//  Fallbacks: fp32-table two-pass, fused fp32.

typedef __attribute__((ext_vector_type(8))) short bf16x8;
typedef __attribute__((ext_vector_type(4))) float f32x4;
typedef __attribute__((ext_vector_type(2))) unsigned int u32x2;
typedef __attribute__((ext_vector_type(4))) unsigned int u32x4;
typedef unsigned long long u64t;

#define HID 64

static __device__ __forceinline__ unsigned short f2bf(float f) {
    __hip_bfloat16 h = __float2bfloat16(f);
    return __builtin_bit_cast(unsigned short, h);
}
static __device__ __forceinline__ unsigned cvt_pk_bf16(float a, float b) {
    unsigned r;
    asm("v_cvt_pk_bf16_f32 %0, %1, %2" : "=v"(r) : "v"(a), "v"(b));
    return r;
}
static __device__ __forceinline__ void lds_fence() {
    asm volatile("s_waitcnt lgkmcnt(0)" ::: "memory");
}
#define MFMA16(a,b,c) __builtin_amdgcn_mfma_f32_16x16x32_bf16((a),(b),(c),0,0,0)

static __device__ __forceinline__ int lswz(int row, int col_shorts) {
    return row * 128 + ((col_shorts * 2) ^ ((row & 7) << 4));
}
static __device__ __forceinline__ f32x4 unpk(u64t q) {
    unsigned lo = (unsigned)q, hi = (unsigned)(q >> 32);
    f32x4 r;
    r[0] = __builtin_bit_cast(float, lo << 16);
    r[1] = __builtin_bit_cast(float, lo & 0xFFFF0000u);
    r[2] = __builtin_bit_cast(float, hi << 16);
    r[3] = __builtin_bit_cast(float, hi & 0xFFFF0000u);
    return r;
}

// ================= weight fragments (shared by MFMA kernels) =================
struct Frags {
    bf16x8 w1f[4];      // L1 B-frags, col-perm h=cl*4+nt; row5=b1 (in8 slot5=1.0)
    bf16x8 w2f[2][4];
    bf16x8 w3f[2];
    float  b2v[4];
    float  b3v;
};

static __device__ __forceinline__ void stage_and_build(
    float* Wst, int tid, int cl, int kg, int hb,
    const float* __restrict__ w1, const float* __restrict__ b1,
    const float* __restrict__ w2, const float* __restrict__ b2,
    const float* __restrict__ w3, const float* __restrict__ b3, Frags& F)
{
    {
        const f32x4* w2v = (const f32x4*)w2;
        f32x4* Wv = (f32x4*)Wst;
        #pragma unroll
        for (int i = 0; i < 4; ++i) Wv[tid + 256 * i] = w2v[tid + 256 * i];
        for (int idx = tid; idx < 320; idx += 256) Wst[4096 + idx] = w1[idx];
        if (tid < 64)  Wst[4416 + tid] = b1[tid];
        if (tid < 192) Wst[4480 + tid] = w3[tid];
        if (tid < 64)  Wst[4672 + tid] = b2[tid];
        if (tid < 3)   Wst[4736 + tid] = b3[tid];
    }
    __syncthreads();

    #pragma unroll
    for (int nt = 0; nt < 4; ++nt) {
        bf16x8 f = {};
        if (kg == 0) {
            #pragma unroll
            for (int j = 0; j < 5; ++j) f[j] = (short)f2bf(Wst[4096 + j * 64 + hb + nt]);
            f[5] = (short)f2bf(Wst[4416 + hb + nt]);
        }
        F.w1f[nt] = f;
    }
    #pragma unroll
    for (int ks = 0; ks < 2; ++ks) {
        f32x4 r[8];
        #pragma unroll
        for (int j = 0; j < 8; ++j)
            r[j] = *(const f32x4*)&Wst[(ks * 32 + kg * 8 + j) * 64 + hb];
        #pragma unroll
        for (int nt = 0; nt < 4; ++nt) {
            u32x4 w;
            #pragma unroll
            for (int jw = 0; jw < 4; ++jw)
                w[jw] = cvt_pk_bf16(r[2 * jw][nt], r[2 * jw + 1][nt]);
            F.w2f[ks][nt] = __builtin_bit_cast(bf16x8, w);
        }
    }
    #pragma unroll
    for (int ks = 0; ks < 2; ++ks) {
        bf16x8 f = {};
        if (cl < 3) {
            #pragma unroll
            for (int j = 0; j < 8; ++j)
                f[j] = (short)f2bf(Wst[4480 + (ks * 32 + kg * 8 + j) * 3 + cl]);
        }
        F.w3f[ks] = f;
    }
    #pragma unroll
    for (int nt = 0; nt < 4; ++nt) F.b2v[nt] = Wst[4672 + hb + nt];
    F.b3v = (cl < 3) ? Wst[4736 + cl] : 0.f;
    __syncthreads();
}

// ======================= pass 0: fp32 emb -> bf16 table =======================
__global__ __launch_bounds__(256) void conv_emb(const f32x4* __restrict__ emb,
                                                u32x2* __restrict__ tab) {
    int t = blockIdx.x * 256 + threadIdx.x;   // 4096 x 256 == 1M exactly
    f32x4 v = emb[t];
    u32x2 p = {cvt_pk_bf16(v[0], v[1]), cvt_pk_bf16(v[2], v[3])};
    tab[t] = p;
}

// ================= pass 1: bilinear gather -> packed bf16 in8 =================
template<int BT>
__global__ __launch_bounds__(256, 4)
void gather3(const float* __restrict__ x, const void* __restrict__ tv,
             u32x4* __restrict__ in8, int n)
{
    const u64t*  __restrict__ tab8 = (const u64t*)tv;
    const f32x4* __restrict__ tabf = (const f32x4*)tv;
    const int S = gridDim.x * 256;
    for (int base = blockIdx.x * 256 + threadIdx.x; base < n; base += 4 * S) {
        float xi[4], xu[4], xv[4];
        #pragma unroll
        for (int j = 0; j < 4; ++j) {
            int pt = base + j * S; int pc = pt < n ? pt : 0;
            const float* xp = x + 3 * pc;
            xi[j] = xp[0]; xu[j] = xp[1]; xv[j] = xp[2];
        }
        u64t  T[4][4];
        f32x4 Fv[4][4];
        float wx[4], wy[4];
        #pragma unroll
        for (int j = 0; j < 4; ++j) {
            float uf = xu[j] * 1024.f, vf = xv[j] * 1024.f;
            int x0 = (int)uf; if (x0 == 1024) x0 = 0;
            int x1 = (x0 + 1 == 1024) ? 1023 : x0 + 1;
            int y0 = (int)vf;
            wx[j] = uf - (float)x0; wy[j] = vf - (float)y0;
            if (y0 > 1023) y0 = 1023;
            int y1 = (y0 + 1 > 1023) ? 1023 : y0 + 1;
            int r0 = y0 << 10, r1 = y1 << 10;
            if (BT) {
                T[j][0] = tab8[r0 + x0]; T[j][1] = tab8[r0 + x1];
                T[j][2] = tab8[r1 + x0]; T[j][3] = tab8[r1 + x1];
            } else {
                Fv[j][0] = tabf[r0 + x0]; Fv[j][1] = tabf[r0 + x1];
                Fv[j][2] = tabf[r1 + x0]; Fv[j][3] = tabf[r1 + x1];
            }
        }
        #pragma unroll
        for (int j = 0; j < 4; ++j) {
            f32x4 A, B, C, D;
            if (BT) { A = unpk(T[j][0]); B = unpk(T[j][1]);
                      C = unpk(T[j][2]); D = unpk(T[j][3]); }
            else    { A = Fv[j][0]; B = Fv[j][1]; C = Fv[j][2]; D = Fv[j][3]; }
            f32x4 up = A + (B - A) * wx[j];
            f32x4 dn = C + (D - C) * wx[j];
            f32x4 g  = up + (dn - up) * wy[j];
            int pt = base + j * S;
            if (pt < n) {
                u32x4 o = {cvt_pk_bf16(xi[j], g[0]), cvt_pk_bf16(g[1], g[2]),
                           cvt_pk_bf16(g[3], 1.0f), 0u};   // slot5=1.0 (bias row)
                in8[pt] = o;
            }
        }
    }
}

// ======================== pass 2: streaming MFMA MLP =========================
// No Lin/Lo staging: A-frags loaded directly from in8 (kg==0 lanes, prefetch
// depth 2); L3 results stored directly to out (wave-coalesced 4B stores).
__global__ __launch_bounds__(256, 4)
void mlp3(const u32x4* __restrict__ in8,
          const float* __restrict__ w1, const float* __restrict__ b1,
          const float* __restrict__ w2, const float* __restrict__ b2,
          const float* __restrict__ w3, const float* __restrict__ b3,
          float* __restrict__ out, int n)
{
    __shared__ __align__(16) short lds_h[4][64][64];   // 32KB: weights stage + h1/h2

    const int tid = threadIdx.x, wid = tid >> 6, lane = tid & 63;
    const int cl = lane & 15, kg = lane >> 4, hb = cl * 4;
    char *LhB = (char*)&lds_h[wid][0][0];

    Frags F;
    stage_and_build((float*)&lds_h[0][0][0], tid, cl, kg, hb, w1, b1, w2, b2, w3, b3, F);

    const int tiles = (n + 63) >> 6;
    const int NW    = gridDim.x * 4;
    const int gw    = blockIdx.x * 4 + wid;

    // A-frag loads for tile t: only kg==0 lanes carry data (B rows k>=8 are 0)
    u32x4 curA[4] = {};
    if (gw < tiles && kg == 0) {
        #pragma unroll
        for (int mt = 0; mt < 4; ++mt) {
            int pt = gw * 64 + mt * 16 + cl;
            curA[mt] = in8[pt < n ? pt : (n - 1)];
        }
    }

    for (int t = gw; t < tiles; t += NW) {
        const int tn = t + NW;
        u32x4 nxtA[4] = {};
        if (tn < tiles && kg == 0) {
            #pragma unroll
            for (int mt = 0; mt < 4; ++mt) {
                int pt = tn * 64 + mt * 16 + cl;
                nxtA[mt] = in8[pt < n ? pt : (n - 1)];
            }
        }

        // -------- L1: K=32 (rows 6..31 zero; kg>=1 A-frags don't matter) --------
        #pragma unroll
        for (int mt = 0; mt < 4; ++mt) {
            bf16x8 af = __builtin_bit_cast(bf16x8, curA[mt]);
            f32x4 acc[4] = {};
            #pragma unroll
            for (int nt = 0; nt < 4; ++nt) acc[nt] = MFMA16(af, F.w1f[nt], acc[nt]);
            #pragma unroll
            for (int r = 0; r < 4; ++r) {
                int row = mt * 16 + kg * 4 + r;
                u32x2 p = {cvt_pk_bf16(fmaxf(acc[0][r], 0.f), fmaxf(acc[1][r], 0.f)),
                           cvt_pk_bf16(fmaxf(acc[2][r], 0.f), fmaxf(acc[3][r], 0.f))};
                *(u32x2*)(LhB + lswz(row, hb)) = p;
            }
        }
        lds_fence();

        // -------- L2: K=64 --------
        #pragma unroll
        for (int mt = 0; mt < 4; ++mt) {
            int arow = mt * 16 + cl;
            bf16x8 a0 = *(const bf16x8*)(LhB + lswz(arow, kg * 8));
            bf16x8 a1 = *(const bf16x8*)(LhB + lswz(arow, 32 + kg * 8));
            f32x4 acc[4];
            #pragma unroll
            for (int nt = 0; nt < 4; ++nt) {
                acc[nt] = (f32x4){F.b2v[nt], F.b2v[nt], F.b2v[nt], F.b2v[nt]};
                acc[nt] = MFMA16(a0, F.w2f[0][nt], acc[nt]);
                acc[nt] = MFMA16(a1, F.w2f[1][nt], acc[nt]);
            }
            #pragma unroll
            for (int r = 0; r < 4; ++r) {
                int row = mt * 16 + kg * 4 + r;
                u32x2 p = {cvt_pk_bf16(fmaxf(acc[0][r], 0.f), fmaxf(acc[1][r], 0.f)),
                           cvt_pk_bf16(fmaxf(acc[2][r], 0.f), fmaxf(acc[3][r], 0.f))};
                *(u32x2*)(LhB + lswz(row, hb)) = p;
            }
        }
        lds_fence();

        // -------- L3: K=64, 3 cols; direct coalesced stores --------
        const int tb = t * 64;
        #pragma unroll
        for (int mt = 0; mt < 4; ++mt) {
            int arow = mt * 16 + cl;
            bf16x8 a0 = *(const bf16x8*)(LhB + lswz(arow, kg * 8));
            bf16x8 a1 = *(const bf16x8*)(LhB + lswz(arow, 32 + kg * 8));
            f32x4 acc = (f32x4){F.b3v, F.b3v, F.b3v, F.b3v};
            acc = MFMA16(a0, F.w3f[0], acc);
            acc = MFMA16(a1, F.w3f[1], acc);
            if (cl < 3) {
                #pragma unroll
                for (int r = 0; r < 4; ++r) {
                    int pt = tb + mt * 16 + kg * 4 + r;
                    if (pt < n) {
                        float s = __builtin_amdgcn_rcpf(1.0f + __expf(-acc[r]));
                        out[pt * 3 + cl] = s;
                    }
                }
            }
        }
        // no fence needed: DS pipe is in-order per wave (next L1 writes follow L3 reads)

        #pragma unroll
        for (int mt = 0; mt < 4; ++mt) curA[mt] = nxtA[mt];
    }
}

// ===================== fallback: fused fp32 (no workspace) =====================
__global__ __launch_bounds__(256, 3)
void fused_fp32(const float* __restrict__ x, const float* __restrict__ emb,
                const float* __restrict__ w1, const float* __restrict__ b1,
                const float* __restrict__ w2, const float* __restrict__ b2,
                const float* __restrict__ w3, const float* __restrict__ b3,
                float* __restrict__ out, int n)
{
    __shared__ __align__(16) short lds_h[4][64][64];
    __shared__ __align__(16) short lds_in[4][64][8];

    const int tid = threadIdx.x, wid = tid >> 6, lane = tid & 63;
    const int cl = lane & 15, kg = lane >> 4, hb = cl * 4;
    char  *LhB = (char*)&lds_h[wid][0][0];
    short *Lin = &lds_in[wid][0][0];
    float *Lo  = (float*)Lin;

    Frags F;
    stage_and_build((float*)&lds_h[0][0][0], tid, cl, kg, hb, w1, b1, w2, b2, w3, b3, F);

    const f32x4* __restrict__ emb4 = (const f32x4*)emb;
    for (int base = blockIdx.x * 256; base < n; base += gridDim.x * 256) {
        const int wbase = base + wid * 64;
        const int pt    = wbase + lane;
        float idf = 0.f, u = 0.f, vv = 0.f;
        if (pt < n) {
            const float* xp = x + 3 * pt;
            idf = xp[0]; u = xp[1]; vv = xp[2];
        }
        float uf = u * 1024.f, vf = vv * 1024.f;
        int x0 = (int)uf; if (x0 == 1024) x0 = 0;
        int x1i = (x0 + 1 == 1024) ? 1023 : x0 + 1;
        int y0 = (int)vf;
        float wx = uf - (float)x0, wy = vf - (float)y0;
        if (y0 > 1023) y0 = 1023;
        int y1 = (y0 + 1 > 1023) ? 1023 : y0 + 1;

        f32x4 v00 = emb4[(y0 << 10) + x0];
        f32x4 v10 = emb4[(y0 << 10) + x1i];
        f32x4 v01 = emb4[(y1 << 10) + x0];
        f32x4 v11 = emb4[(y1 << 10) + x1i];
        f32x4 vup = v00 + (v10 - v00) * wx;
        f32x4 vdn = v01 + (v11 - v01) * wx;
        f32x4 g   = vup + (vdn - vup) * wy;

        u32x4 inq = {cvt_pk_bf16(idf, g[0]), cvt_pk_bf16(g[1], g[2]),
                     cvt_pk_bf16(g[3], 1.0f), 0u};
        *(u32x4*)(Lin + lane * 8) = inq;
        lds_fence();

        #pragma unroll
        for (int mt = 0; mt < 4; ++mt) {
            bf16x8 af = {};
            if (kg == 0) af = *(const bf16x8*)(Lin + (mt * 16 + cl) * 8);
            f32x4 acc[4] = {};
            #pragma unroll
            for (int nt = 0; nt < 4; ++nt) acc[nt] = MFMA16(af, F.w1f[nt], acc[nt]);
            #pragma unroll
            for (int r = 0; r < 4; ++r) {
                int row = mt * 16 + kg * 4 + r;
                u32x2 p = {cvt_pk_bf16(fmaxf(acc[0][r], 0.f), fmaxf(acc[1][r], 0.f)),
                           cvt_pk_bf16(fmaxf(acc[2][r], 0.f), fmaxf(acc[3][r], 0.f))};
                *(u32x2*)(LhB + lswz(row, hb)) = p;
            }
        }
        lds_fence();
        #pragma unroll
        for (int mt = 0; mt < 4; ++mt) {
            int arow = mt * 16 + cl;
            bf16x8 a0 = *(const bf16x8*)(LhB + lswz(arow, kg * 8));
            bf16x8 a1 = *(const bf16x8*)(LhB + lswz(arow, 32 + kg * 8));
            f32x4 acc[4];
            #pragma unroll
            for (int nt = 0; nt < 4; ++nt) {
                acc[nt] = (f32x4){F.b2v[nt], F.b2v[nt], F.b2v[nt], F.b2v[nt]};
                acc[nt] = MFMA16(a0, F.w2f[0][nt], acc[nt]);
                acc[nt] = MFMA16(a1, F.w2f[1][nt], acc[nt]);
            }
            #pragma unroll
            for (int r = 0; r < 4; ++r) {
                int row = mt * 16 + kg * 4 + r;
                u32x2 p = {cvt_pk_bf16(fmaxf(acc[0][r], 0.f), fmaxf(acc[1][r], 0.f)),
                           cvt_pk_bf16(fmaxf(acc[2][r], 0.f), fmaxf(acc[3][r], 0.f))};
                *(u32x2*)(LhB + lswz(row, hb)) = p;
            }
        }
        lds_fence();
        #pragma unroll
        for (int mt = 0; mt < 4; ++mt) {
            int arow = mt * 16 + cl;
            bf16x8 a0 = *(const bf16x8*)(LhB + lswz(arow, kg * 8));
            bf16x8 a1 = *(const bf16x8*)(LhB + lswz(arow, 32 + kg * 8));
            f32x4 acc = (f32x4){F.b3v, F.b3v, F.b3v, F.b3v};
            acc = MFMA16(a0, F.w3f[0], acc);
            acc = MFMA16(a1, F.w3f[1], acc);
            if (cl < 3) {
                #pragma unroll
                for (int r = 0; r < 4; ++r) {
                    int pt2 = wbase + mt * 16 + kg * 4 + r;
                    if (pt2 < n) {
                        float s = __builtin_amdgcn_rcpf(1.0f + __expf(-acc[r]));
                        out[pt2 * 3 + cl] = s;
                    }
                }
            }
        }
    }
}

extern "C" void kernel_launch(void* const* d_in, const int* in_sizes, int n_in,
                              void* d_out, int out_size, void* d_ws, size_t ws_size,
                              hipStream_t stream) {
    const float* x   = (const float*)d_in[0];
    const float* emb = (const float*)d_in[1];
    const float* w1  = (const float*)d_in[2];
    const float* b1  = (const float*)d_in[3];
    const float* w2  = (const float*)d_in[4];
    const float* b2  = (const float*)d_in[5];
    const float* w3  = (const float*)d_in[6];
    const float* b3  = (const float*)d_in[7];
    float* out = (float*)d_out;

    int n = in_sizes[0] / 3;
    const size_t tab_bytes = (size_t)8 * 1024 * 1024;
    const size_t in8_bytes = (size_t)n * 16;

    int nblkG = (n + 1023) / 1024; if (nblkG > 4096) nblkG = 4096;
    if (nblkG < 1) nblkG = 1;
    int tiles = (n + 63) / 64;
    int nblkM = 1024;
    if (nblkM * 4 > tiles) nblkM = (tiles + 3) / 4;
    if (nblkM < 1) nblkM = 1;

    if (ws_size >= tab_bytes + in8_bytes) {
        u32x4* in8 = (u32x4*)((char*)d_ws + tab_bytes);
        conv_emb<<<dim3(4096), dim3(256), 0, stream>>>((const f32x4*)emb, (u32x2*)d_ws);
        gather3<1><<<dim3(nblkG), dim3(256), 0, stream>>>(x, d_ws, in8, n);
        mlp3<<<dim3(nblkM), dim3(256), 0, stream>>>(in8, w1, b1, w2, b2, w3, b3, out, n);
    } else if (ws_size >= in8_bytes) {
        u32x4* in8 = (u32x4*)d_ws;
        gather3<0><<<dim3(nblkG), dim3(256), 0, stream>>>(x, emb, in8, n);
        mlp3<<<dim3(nblkM), dim3(256), 0, stream>>>(in8, w1, b1, w2, b2, w3, b3, out, n);
    } else {
        int nblk = (n + 255) / 256; if (nblk > 2048) nblk = 2048;
        fused_fp32<<<dim3(nblk), dim3(256), 0, stream>>>(
            x, emb, w1, b1, w2, b2, w3, b3, out, n);
    }
}

// Round 9
// 74.090 us; speedup vs baseline: 1.6210x; 1.6210x over previous
//
#include <hip/hip_runtime.h>
#include <hip/hip_bf16.h>

// DenseGridNet R9: fused gather + transposed in-register MFMA MLP.
// C^T = W^T X^T formulation: with hid-permutation kappa, each layer's C/D
// fragments are the next layer's B fragments in the same lanes (relu+cvt_pk
// only). No LDS/fences between layers; one 16B/lane LDS transpose per tile.

typedef __attribute__((ext_vector_type(8))) short bf16x8;
typedef __attribute__((ext_vector_type(4))) float f32x4;
typedef __attribute__((ext_vector_type(2))) unsigned int u32x2;
typedef __attribute__((ext_vector_type(4))) unsigned int u32x4;
typedef unsigned long long u64t;

#define HID 64

static __device__ __forceinline__ unsigned short f2bf(float f) {
    __hip_bfloat16 h = __float2bfloat16(f);
    return __builtin_bit_cast(unsigned short, h);
}
static __device__ __forceinline__ unsigned cvt_pk_bf16(float a, float b) {
    unsigned r;
    asm("v_cvt_pk_bf16_f32 %0, %1, %2" : "=v"(r) : "v"(a), "v"(b));
    return r;
}
static __device__ __forceinline__ void lds_fence() {
    asm volatile("s_waitcnt lgkmcnt(0)" ::: "memory");
}
#define MFMA16(a,b,c) __builtin_amdgcn_mfma_f32_16x16x32_bf16((a),(b),(c),0,0,0)

static __device__ __forceinline__ f32x4 unpk(u64t q) {
    unsigned lo = (unsigned)q, hi = (unsigned)(q >> 32);
    f32x4 r;
    r[0] = __builtin_bit_cast(float, lo << 16);
    r[1] = __builtin_bit_cast(float, lo & 0xFFFF0000u);
    r[2] = __builtin_bit_cast(float, hi << 16);
    r[3] = __builtin_bit_cast(float, hi & 0xFFFF0000u);
    return r;
}
// relu + pack two f32x4 accs into one B-frag (k-order: lo[0..3], hi[0..3])
static __device__ __forceinline__ bf16x8 pack_pair(f32x4 lo, f32x4 hi) {
    u32x4 w;
    w[0] = cvt_pk_bf16(fmaxf(lo[0], 0.f), fmaxf(lo[1], 0.f));
    w[1] = cvt_pk_bf16(fmaxf(lo[2], 0.f), fmaxf(lo[3], 0.f));
    w[2] = cvt_pk_bf16(fmaxf(hi[0], 0.f), fmaxf(hi[1], 0.f));
    w[3] = cvt_pk_bf16(fmaxf(hi[2], 0.f), fmaxf(hi[3], 0.f));
    return __builtin_bit_cast(bf16x8, w);
}

// ---- weight A-fragments for the transposed scheme (built once per block) ----
struct TFrags {
    bf16x8 a1[4];        // W1^T rows mt*16+cl, k=0..5 (idf,g0..3,bias-row)
    bf16x8 a2[4][2];     // W2^T, K in kappa order: [mt2][ks]
    bf16x8 a3[2];        // W3^T (rows 0..2 valid), kappa order
    f32x4  bias2[4];     // b2 at hid2 = mt2*16+kg*4+r
    f32x4  bias3;        // b3 at ch = kg*4+r (kg==0, r<3)
};

// Wst layout (floats): [0..4095]=w2, [4096..4415]=w1, [4416..4479]=b1,
//                      [4480..4671]=w3, [4672..4735]=b2, [4736..4738]=b3
static __device__ __forceinline__ void build_tfrags(
    float* Wst, int tid, int cl, int kg,
    const float* __restrict__ w1, const float* __restrict__ b1,
    const float* __restrict__ w2, const float* __restrict__ b2,
    const float* __restrict__ w3, const float* __restrict__ b3, TFrags& F)
{
    {
        const f32x4* w2v = (const f32x4*)w2;
        f32x4* Wv = (f32x4*)Wst;
        #pragma unroll
        for (int i = 0; i < 4; ++i) Wv[tid + 256 * i] = w2v[tid + 256 * i];
        for (int idx = tid; idx < 320; idx += 256) Wst[4096 + idx] = w1[idx];
        if (tid < 64)  Wst[4416 + tid] = b1[tid];
        if (tid < 192) Wst[4480 + tid] = w3[tid];
        if (tid < 64)  Wst[4672 + tid] = b2[tid];
        if (tid < 3)   Wst[4736 + tid] = b3[tid];
    }
    __syncthreads();

    #pragma unroll
    for (int mt = 0; mt < 4; ++mt) {
        bf16x8 f = {};
        if (kg == 0) {
            int hid = mt * 16 + cl;
            #pragma unroll
            for (int j = 0; j < 5; ++j) f[j] = (short)f2bf(Wst[4096 + j * 64 + hid]);
            f[5] = (short)f2bf(Wst[4416 + hid]);   // bias row (input slot5 = 1.0)
        }
        F.a1[mt] = f;
    }
    #pragma unroll
    for (int ks = 0; ks < 2; ++ks) {
        #pragma unroll
        for (int mt2 = 0; mt2 < 4; ++mt2) {
            bf16x8 f;
            #pragma unroll
            for (int j = 0; j < 8; ++j) {
                int kap = (2 * ks + (j >> 2)) * 16 + kg * 4 + (j & 3);
                f[j] = (short)f2bf(Wst[kap * 64 + mt2 * 16 + cl]);
            }
            F.a2[mt2][ks] = f;
        }
        bf16x8 f3 = {};
        if (cl < 3) {
            #pragma unroll
            for (int j = 0; j < 8; ++j) {
                int kap = (2 * ks + (j >> 2)) * 16 + kg * 4 + (j & 3);
                f3[j] = (short)f2bf(Wst[4480 + kap * 3 + cl]);
            }
        }
        F.a3[ks] = f3;
    }
    #pragma unroll
    for (int mt2 = 0; mt2 < 4; ++mt2) {
        f32x4 b;
        #pragma unroll
        for (int r = 0; r < 4; ++r) b[r] = Wst[4672 + mt2 * 16 + kg * 4 + r];
        F.bias2[mt2] = b;
    }
    {
        f32x4 b = {};
        if (kg == 0) { b[0] = Wst[4736]; b[1] = Wst[4737]; b[2] = Wst[4738]; }
        F.bias3 = b;
    }
    __syncthreads();
}

// ------------------- pass 0: fp32 emb -> bf16 table (8 MB) -------------------
__global__ __launch_bounds__(256) void conv_emb(const f32x4* __restrict__ emb,
                                                u32x2* __restrict__ tab) {
    int t = blockIdx.x * 256 + threadIdx.x;   // 4096 x 256 == 1M exactly
    f32x4 v = emb[t];
    u32x2 p = {cvt_pk_bf16(v[0], v[1]), cvt_pk_bf16(v[2], v[3])};
    tab[t] = p;
}

// ------------------------------ fused kernel --------------------------------
template<int BT>
__global__ __launch_bounds__(256, 3)
void dgn_fused(const float* __restrict__ x, const void* __restrict__ tabv,
               const float* __restrict__ w1, const float* __restrict__ b1,
               const float* __restrict__ w2, const float* __restrict__ b2,
               const float* __restrict__ w3, const float* __restrict__ b3,
               float* __restrict__ out, int n)
{
    __shared__ __align__(16) float Wst[4768];   // 19 KB; reused as Xf after build

    const int tid = threadIdx.x, wid = tid >> 6, lane = tid & 63;
    const int cl = lane & 15, kg = lane >> 4;

    TFrags F;
    build_tfrags(Wst, tid, cl, kg, w1, b1, w2, b2, w3, b3, F);

    u32x4* Xf = (u32x4*)Wst + wid * 64;   // per-wave 1 KB transpose buffer

    const u64t*  __restrict__ tab8 = (const u64t*)tabv;
    const f32x4* __restrict__ tabf = (const f32x4*)tabv;

    const int SP   = gridDim.x * 256;
    const int blk0 = blockIdx.x * 256;
    if (blk0 >= n) return;
    const int iters = (n - blk0 + SP - 1) / SP;
    const int wb0   = blk0 + wid * 64;

    #define LOADX(I, A, B, C) { int pt_ = wb0 + (I) * SP + lane;                \
        int pc_ = pt_ < n ? pt_ : 0; const float* xp_ = x + 3 * pc_;            \
        A = xp_[0]; B = xp_[1]; C = xp_[2]; }

    #define GISSUE(U, V, T, Fv, WX, WY) {                                       \
        float uf_ = (U) * 1024.f, vf_ = (V) * 1024.f;                           \
        int x0_ = (int)uf_; if (x0_ == 1024) x0_ = 0;                           \
        int x1_ = (x0_ + 1 == 1024) ? 1023 : x0_ + 1;                           \
        int y0_ = (int)vf_;                                                     \
        WX = uf_ - (float)x0_; WY = vf_ - (float)y0_;                           \
        if (y0_ > 1023) y0_ = 1023;                                             \
        int y1_ = (y0_ + 1 > 1023) ? 1023 : y0_ + 1;                            \
        int r0_ = y0_ << 10, r1_ = y1_ << 10;                                   \
        if (BT) { T[0] = tab8[r0_ + x0_]; T[1] = tab8[r0_ + x1_];               \
                  T[2] = tab8[r1_ + x0_]; T[3] = tab8[r1_ + x1_]; }             \
        else    { Fv[0] = tabf[r0_ + x0_]; Fv[1] = tabf[r0_ + x1_];             \
                  Fv[2] = tabf[r1_ + x0_]; Fv[3] = tabf[r1_ + x1_]; } }

    // -------- depth-2 pipeline prologue --------
    u64t  cT[4] = {};  f32x4 cF[4] = {};
    float cwx, cwy, cid;
    float nx0, nx1, nx2;
    {
        float p0, p1, p2;
        LOADX(0, p0, p1, p2);
        GISSUE(p1, p2, cT, cF, cwx, cwy);
        cid = p0;
        LOADX(1, nx0, nx1, nx2);
    }

    for (int i = 0; i < iters; ++i) {
        // issue next tile's texel loads + x(i+2) before this tile's MLP
        u64t  tT[4] = {};  f32x4 tF[4] = {};
        float twx = 0.f, twy = 0.f, tcid = 0.f;
        const bool more = (i + 1 < iters);
        if (more) {
            GISSUE(nx1, nx2, tT, tF, twx, twy);
            tcid = nx0;
            int nix = (i + 2 < iters) ? i + 2 : i + 1;
            LOADX(nix, nx0, nx1, nx2);
        }

        // -------- current tile: lerp + pack + lane-transpose via LDS --------
        f32x4 A, B, C, D;
        if (BT) { A = unpk(cT[0]); B = unpk(cT[1]); C = unpk(cT[2]); D = unpk(cT[3]); }
        else    { A = cF[0]; B = cF[1]; C = cF[2]; D = cF[3]; }
        f32x4 up = A + (B - A) * cwx;
        f32x4 dn = C + (D - C) * cwx;
        f32x4 g  = up + (dn - up) * cwy;

        u32x4 inq = {cvt_pk_bf16(cid, g[0]), cvt_pk_bf16(g[1], g[2]),
                     cvt_pk_bf16(g[3], 1.0f), 0u};   // slot5 = 1.0 (bias row)
        Xf[lane] = inq;
        lds_fence();
        // B-frags for L1: lane (cl,kg) needs point nt*16+cl (kg>=1 rows killed
        // by zero A columns k>=6; same-addr 4-way read = broadcast, free)
        u32x4 bq0 = Xf[0 * 16 + cl];
        u32x4 bq1 = Xf[1 * 16 + cl];
        u32x4 bq2 = Xf[2 * 16 + cl];
        u32x4 bq3 = Xf[3 * 16 + cl];

        // -------- MLP: per point-tile nt, fully in registers --------
        const int tb = wb0 + i * SP;
        #pragma unroll
        for (int nt = 0; nt < 4; ++nt) {
            u32x4 bqs = (nt == 0) ? bq0 : (nt == 1) ? bq1 : (nt == 2) ? bq2 : bq3;
            bf16x8 bb = __builtin_bit_cast(bf16x8, bqs);

            // L1: C1^T[hid][pt] ; acc init 0 (b1 rides k=5)
            f32x4 c1_0 = {}, c1_1 = {}, c1_2 = {}, c1_3 = {};
            c1_0 = MFMA16(F.a1[0], bb, c1_0);
            c1_1 = MFMA16(F.a1[1], bb, c1_1);
            c1_2 = MFMA16(F.a1[2], bb, c1_2);
            c1_3 = MFMA16(F.a1[3], bb, c1_3);

            // relu+pack -> L2 B-frags (kappa order)
            bf16x8 p0 = pack_pair(c1_0, c1_1);
            bf16x8 p1 = pack_pair(c1_2, c1_3);

            // L2: K=64 (2 k-steps), bias via acc init
            f32x4 c2_0 = F.bias2[0], c2_1 = F.bias2[1],
                  c2_2 = F.bias2[2], c2_3 = F.bias2[3];
            c2_0 = MFMA16(F.a2[0][0], p0, c2_0); c2_0 = MFMA16(F.a2[0][1], p1, c2_0);
            c2_1 = MFMA16(F.a2[1][0], p0, c2_1); c2_1 = MFMA16(F.a2[1][1], p1, c2_1);
            c2_2 = MFMA16(F.a2[2][0], p0, c2_2); c2_2 = MFMA16(F.a2[2][1], p1, c2_2);
            c2_3 = MFMA16(F.a2[3][0], p0, c2_3); c2_3 = MFMA16(F.a2[3][1], p1, c2_3);

            // relu+pack -> L3 B-frags
            bf16x8 q0 = pack_pair(c2_0, c2_1);
            bf16x8 q1 = pack_pair(c2_2, c2_3);

            // L3: 3 output channels (rows 0..2), bias via acc init
            f32x4 c3 = F.bias3;
            c3 = MFMA16(F.a3[0], q0, c3);
            c3 = MFMA16(F.a3[1], q1, c3);

            // sigmoid + store: kg==0 lane cl owns point tb+nt*16+cl, ch=r
            if (kg == 0) {
                int pt = tb + nt * 16 + cl;
                if (pt < n) {
                    #pragma unroll
                    for (int r = 0; r < 3; ++r) {
                        float s = __builtin_amdgcn_rcpf(1.0f + __expf(-c3[r]));
                        out[pt * 3 + r] = s;
                    }
                }
            }
        }

        if (more) {
            #pragma unroll
            for (int j = 0; j < 4; ++j) { cT[j] = tT[j]; cF[j] = tF[j]; }
            cwx = twx; cwy = twy; cid = tcid;
        }
    }
    #undef LOADX
    #undef GISSUE
}

extern "C" void kernel_launch(void* const* d_in, const int* in_sizes, int n_in,
                              void* d_out, int out_size, void* d_ws, size_t ws_size,
                              hipStream_t stream) {
    const float* x   = (const float*)d_in[0];
    const float* emb = (const float*)d_in[1];
    const float* w1  = (const float*)d_in[2];
    const float* b1  = (const float*)d_in[3];
    const float* w2  = (const float*)d_in[4];
    const float* b2  = (const float*)d_in[5];
    const float* w3  = (const float*)d_in[6];
    const float* b3  = (const float*)d_in[7];
    float* out = (float*)d_out;

    int n = in_sizes[0] / 3;
    int nblk = (n + 255) / 256;
    if (nblk > 768) nblk = 768;   // 3 blocks/CU resident, one dispatch round

    const size_t tab_bytes = (size_t)8 * 1024 * 1024;
    if (ws_size >= tab_bytes) {
        conv_emb<<<dim3(4096), dim3(256), 0, stream>>>((const f32x4*)emb, (u32x2*)d_ws);
        dgn_fused<1><<<dim3(nblk), dim3(256), 0, stream>>>(
            x, d_ws, w1, b1, w2, b2, w3, b3, out, n);
    } else {
        dgn_fused<0><<<dim3(nblk), dim3(256), 0, stream>>>(
            x, emb, w1, b1, w2, b2, w3, b3, out, n);
    }
}